// Round 1
// 299.653 us; speedup vs baseline: 1.0996x; 1.0996x over previous
//
#include <hip/hip_runtime.h>
#include <math.h>

#define N_NODES 50000
#define N_EDGES 800000
#define D_IN    256
#define D_HID   128
#define D_OUT   64

typedef unsigned int u32;
typedef unsigned short u16;
typedef __attribute__((ext_vector_type(8))) short bf16x8;   // 8 bf16 = 4 VGPRs
typedef __attribute__((ext_vector_type(4))) float f32x4;

__device__ __forceinline__ float bflo(u32 u) {
    union { u32 i; float f; } c; c.i = u << 16; return c.f;
}
__device__ __forceinline__ float bfhi(u32 u) {
    union { u32 i; float f; } c; c.i = u & 0xffff0000u; return c.f;
}
__device__ __forceinline__ u32 pack_bf2(float a, float b) {
    union { float f; u32 i; } ca, cb; ca.f = a; cb.f = b;
    u32 ra = (ca.i + 0x7fffu + ((ca.i >> 16) & 1u)) >> 16;
    u32 rb = (cb.i + 0x7fffu + ((cb.i >> 16) & 1u)) & 0xffff0000u;
    return ra | rb;
}
__device__ __forceinline__ u32 bf16_rne(float f) {
    union { float f; u32 i; } c; c.f = f;
    return (c.i + 0x7fffu + ((c.i >> 16) & 1u)) >> 16;
}
__device__ __forceinline__ float bfbits_to_f32(u32 hb) {
    union { u32 i; float f; } c; c.i = hb << 16; return c.f;
}

// ---------------- edge dtype detection ----------------
__global__ void k_detect(const void* __restrict__ ei, int* __restrict__ flag) {
    int t = threadIdx.x;
    int v = ((const int*)ei)[2 * t + 1];
    if (v != 0) atomicOr(flag, 1);
}

__device__ __forceinline__ int edge_at(const void* ei, int is64, int which, int i) {
    if (is64) return (int)((const long long*)ei)[(size_t)which * N_EDGES + i];
    return ((const int*)ei)[which * N_EDGES + i];
}

// ---------------- degree / CSR build ----------------

__global__ void k_count(const void* __restrict__ ei, const int* __restrict__ flag,
                        int* __restrict__ cnt) {
    int i = blockIdx.x * blockDim.x + threadIdx.x;
    int is64 = (flag[0] == 0);
    if (i < N_EDGES) atomicAdd(&cnt[edge_at(ei, is64, 1, i)], 1);
}

__global__ void k_dinv(const int* __restrict__ cnt, float* __restrict__ dinv) {
    int i = blockIdx.x * blockDim.x + threadIdx.x;
    if (i < N_NODES) dinv[i] = rsqrtf(1.0f + (float)cnt[i]);
}

#define SCAN_B 256
__global__ void k_scan1(const int* __restrict__ cnt, int* __restrict__ ex,
                        int* __restrict__ partials, int n) {
    __shared__ int sm[SCAN_B];
    int t = threadIdx.x;
    int i = blockIdx.x * SCAN_B + t;
    int v = (i < n) ? cnt[i] : 0;
    sm[t] = v; __syncthreads();
    for (int off = 1; off < SCAN_B; off <<= 1) {
        int add = (t >= off) ? sm[t - off] : 0;
        __syncthreads();
        sm[t] += add;
        __syncthreads();
    }
    if (i < n) ex[i] = sm[t] - v;
    if (t == SCAN_B - 1) partials[blockIdx.x] = sm[t];
}

__global__ void k_scan2(int* __restrict__ partials, int nb) {
    __shared__ int sm[SCAN_B];
    int t = threadIdx.x;
    int v = (t < nb) ? partials[t] : 0;
    sm[t] = v; __syncthreads();
    for (int off = 1; off < SCAN_B; off <<= 1) {
        int add = (t >= off) ? sm[t - off] : 0;
        __syncthreads();
        sm[t] += add;
        __syncthreads();
    }
    if (t < nb) partials[t] = sm[t] - v;
}

__global__ void k_scan3(int* __restrict__ ex, const int* __restrict__ partials, int n) {
    int i = blockIdx.x * SCAN_B + threadIdx.x;
    if (i < n) ex[i] += partials[blockIdx.x];
}

__global__ void k_fill(const void* __restrict__ ei, const int* __restrict__ flag,
                       const int* __restrict__ rowstart, int* __restrict__ cursor,
                       int* __restrict__ colidx) {
    int i = blockIdx.x * blockDim.x + threadIdx.x;
    int is64 = (flag[0] == 0);
    if (i < N_EDGES) {
        int s = edge_at(ei, is64, 0, i);
        int d = edge_at(ei, is64, 1, i);
        int pos = rowstart[d] + atomicAdd(&cursor[d], 1);
        colidx[pos] = s;
    }
}

// ---------------- W pre-split: W[k][c] f32 -> Wt_hi/Wt_lo[c][k] bf16 ----------------
__global__ void k_wsplit(const float* __restrict__ W, u16* __restrict__ tHi,
                         u16* __restrict__ tLo, int K, int NF) {
    int i = blockIdx.x * 256 + threadIdx.x;
    if (i >= K * NF) return;
    int k = i / NF, c = i - k * NF;
    float f = W[i];
    u32 hb = bf16_rne(f);
    u32 lb = bf16_rne(f - bfbits_to_f32(hb));
    tHi[(size_t)c * K + k] = (u16)hb;
    tLo[(size_t)c * K + k] = (u16)lb;
}

// ---- MFMA GEMM: Cp[r,:] = pack_bf16( (A[r,:] @ W) * dinv[r] ), split-bf16 3-term ----
// BM=128 rows/block, 4 waves of 32 rows x NF cols. K-step 32.
// A staged f32->hi/lo bf16 in LDS [row][k] (stride 40 bf16 = bank stride 20, ~2-way).
// W staged from pre-transposed [col][k] bf16 arrays.
// mfma_f32_16x16x32_bf16 layouts: A lane: row=lane&15, k=(lane>>4)*8+[0..7];
// B lane: col=lane&15, k=(lane>>4)*8+[0..7]; D lane: col=lane&15, row=(lane>>4)*4+reg.
template <int K, int NF>
__global__ __launch_bounds__(256) void k_gemm_mfma(
    const float* __restrict__ A, const u16* __restrict__ tHi,
    const u16* __restrict__ tLo, const float* __restrict__ dinv,
    u32* __restrict__ Cp, int M) {
    constexpr int NT = NF / 16;
    constexpr int LDK = 40;
    __shared__ u16 aH[128][LDK], aL[128][LDK];
    __shared__ u16 wH[NF][LDK], wL[NF][LDK];

    const int t = threadIdx.x;
    const int lane = t & 63, wv = t >> 6;
    const int m0 = blockIdx.x * 128;
    const int lr = lane & 15, lk = (lane >> 4) * 8;

    f32x4 acc[2][NT] = {};

    // A-staging assignment: thread -> (row, 16-wide k chunk)
    const int arow = t >> 1;
    const int akq = (t & 1) * 16;
    const bool aok = (m0 + arow) < M;
    const float* asrc = A + (size_t)(m0 + arow) * K + akq;

    for (int ks = 0; ks < K; ks += 32) {
        // ---- stage A tile: 128 x 32 f32 -> hi/lo bf16 ----
        {
            float buf[16];
            #pragma unroll
            for (int j = 0; j < 16; ++j) buf[j] = 0.0f;
            if (aok) {
                const float4* p = (const float4*)(asrc + ks);
                float4 v0 = p[0], v1 = p[1], v2 = p[2], v3 = p[3];
                buf[0] = v0.x; buf[1] = v0.y; buf[2]  = v0.z; buf[3]  = v0.w;
                buf[4] = v1.x; buf[5] = v1.y; buf[6]  = v1.z; buf[7]  = v1.w;
                buf[8] = v2.x; buf[9] = v2.y; buf[10] = v2.z; buf[11] = v2.w;
                buf[12] = v3.x; buf[13] = v3.y; buf[14] = v3.z; buf[15] = v3.w;
            }
            u32 h[16], l[16];
            #pragma unroll
            for (int j = 0; j < 16; ++j) {
                h[j] = bf16_rne(buf[j]);
                l[j] = bf16_rne(buf[j] - bfbits_to_f32(h[j]));
            }
            uint4 hv0 = make_uint4(h[0] | (h[1] << 16), h[2] | (h[3] << 16),
                                   h[4] | (h[5] << 16), h[6] | (h[7] << 16));
            uint4 hv1 = make_uint4(h[8] | (h[9] << 16), h[10] | (h[11] << 16),
                                   h[12] | (h[13] << 16), h[14] | (h[15] << 16));
            uint4 lv0 = make_uint4(l[0] | (l[1] << 16), l[2] | (l[3] << 16),
                                   l[4] | (l[5] << 16), l[6] | (l[7] << 16));
            uint4 lv1 = make_uint4(l[8] | (l[9] << 16), l[10] | (l[11] << 16),
                                   l[12] | (l[13] << 16), l[14] | (l[15] << 16));
            *(uint4*)&aH[arow][akq + 0] = hv0;
            *(uint4*)&aH[arow][akq + 8] = hv1;
            *(uint4*)&aL[arow][akq + 0] = lv0;
            *(uint4*)&aL[arow][akq + 8] = lv1;
        }
        // ---- stage W tile: NF cols x 32 k, hi+lo ----
        #pragma unroll
        for (int idx = t; idx < NF * 4; idx += 256) {
            int col = idx >> 2;
            int k8 = (idx & 3) * 8;
            *(uint4*)&wH[col][k8] = *(const uint4*)&tHi[(size_t)col * K + ks + k8];
            *(uint4*)&wL[col][k8] = *(const uint4*)&tLo[(size_t)col * K + ks + k8];
        }
        __syncthreads();

        bf16x8 afH[2], afL[2];
        #pragma unroll
        for (int mt = 0; mt < 2; ++mt) {
            int r = wv * 32 + mt * 16 + lr;
            afH[mt] = *(const bf16x8*)&aH[r][lk];
            afL[mt] = *(const bf16x8*)&aL[r][lk];
        }
        #pragma unroll
        for (int nt = 0; nt < NT; ++nt) {
            bf16x8 bh = *(const bf16x8*)&wH[nt * 16 + lr][lk];
            bf16x8 bl = *(const bf16x8*)&wL[nt * 16 + lr][lk];
            #pragma unroll
            for (int mt = 0; mt < 2; ++mt) {
                acc[mt][nt] = __builtin_amdgcn_mfma_f32_16x16x32_bf16(afH[mt], bh, acc[mt][nt], 0, 0, 0);
                acc[mt][nt] = __builtin_amdgcn_mfma_f32_16x16x32_bf16(afL[mt], bh, acc[mt][nt], 0, 0, 0);
                acc[mt][nt] = __builtin_amdgcn_mfma_f32_16x16x32_bf16(afH[mt], bl, acc[mt][nt], 0, 0, 0);
            }
        }
        __syncthreads();
    }

    // ---- epilogue: scale by dinv, pack adjacent col pairs, store ----
    #pragma unroll
    for (int mt = 0; mt < 2; ++mt) {
        #pragma unroll
        for (int r = 0; r < 4; ++r) {
            int row = m0 + wv * 32 + mt * 16 + (lane >> 4) * 4 + r;
            float dv = (row < M) ? dinv[row] : 0.0f;
            #pragma unroll
            for (int nt = 0; nt < NT; ++nt) {
                float v = acc[mt][nt][r] * dv;
                float vn = __shfl_xor(v, 1);
                if (!(lane & 1) && row < M) {
                    Cp[(size_t)row * (NF / 2) + nt * 8 + (lr >> 1)] = pack_bf2(v, vn);
                }
            }
        }
    }
}

// ---------------- fused aggregate + bias (+relu) + sigmoid gate ----------------
// hs rows are pre-scaled by dinv[row]; agg = dv * (hs[v] + sum hs[neighbor]).

// layer 1: 128 feats = 64 u32/row. One wave per node; lane l = feats (2l, 2l+1).
__global__ void k_agg1(const u32* __restrict__ hs, const int* __restrict__ rowstart,
                       const int* __restrict__ cnt, const int* __restrict__ colidx,
                       const float* __restrict__ dinv,
                       const float* __restrict__ b, const float* __restrict__ aw,
                       const float* __restrict__ ab, float* __restrict__ out) {
    int v = blockIdx.x;
    int l = threadIdx.x;
    float dv = dinv[v];
    u32 su = hs[(size_t)v * 64 + l];
    float ax = bflo(su), ay = bfhi(su);
    int start = rowstart[v], len = cnt[v];
    const int* cx = colidx + start;
    int j = 0;
    for (; j + 4 <= len; j += 4) {
        int s0 = cx[j], s1 = cx[j + 1], s2 = cx[j + 2], s3 = cx[j + 3];
        u32 u0 = hs[(size_t)s0 * 64 + l];
        u32 u1 = hs[(size_t)s1 * 64 + l];
        u32 u2 = hs[(size_t)s2 * 64 + l];
        u32 u3 = hs[(size_t)s3 * 64 + l];
        ax += bflo(u0) + bflo(u1) + bflo(u2) + bflo(u3);
        ay += bfhi(u0) + bfhi(u1) + bfhi(u2) + bfhi(u3);
    }
    for (; j < len; ++j) {
        u32 u = hs[(size_t)cx[j] * 64 + l];
        ax += bflo(u); ay += bfhi(u);
    }
    float2 bp = ((const float2*)b)[l];
    ax = fmaxf(ax * dv + bp.x, 0.0f);
    ay = fmaxf(ay * dv + bp.y, 0.0f);
    float2 ap = ((const float2*)aw)[l];
    float p = ax * ap.x + ay * ap.y;
    for (int off = 32; off; off >>= 1) p += __shfl_xor(p, off);
    float g = 1.0f / (1.0f + expf(-(p + ab[0])));
    ((float2*)out)[(size_t)v * 64 + l] = make_float2(ax * g, ay * g);
}

// layer 2: 64 feats = 32 u32/row. One wave per node, split into 2 half-waves
// that process alternating neighbors (2 rows in flight, x2 unroll = 4).
__global__ void k_agg2(const u32* __restrict__ hs, const int* __restrict__ rowstart,
                       const int* __restrict__ cnt, const int* __restrict__ colidx,
                       const float* __restrict__ dinv,
                       const float* __restrict__ b, const float* __restrict__ aw,
                       const float* __restrict__ ab, float* __restrict__ out) {
    int v = blockIdx.x;
    int l = threadIdx.x;
    int c = l & 31, half = l >> 5;
    float dv = dinv[v];
    float ax = 0.0f, ay = 0.0f;
    if (half == 0) {
        u32 su = hs[(size_t)v * 32 + c];
        ax = bflo(su); ay = bfhi(su);
    }
    int start = rowstart[v], len = cnt[v];
    const int* cx = colidx + start;
    int j = half;
    for (; j + 2 < len; j += 4) {
        int s0 = cx[j], s1 = cx[j + 2];
        u32 u0 = hs[(size_t)s0 * 32 + c];
        u32 u1 = hs[(size_t)s1 * 32 + c];
        ax += bflo(u0) + bflo(u1);
        ay += bfhi(u0) + bfhi(u1);
    }
    if (j < len) {
        u32 u = hs[(size_t)cx[j] * 32 + c];
        ax += bflo(u); ay += bfhi(u);
    }
    ax += __shfl_xor(ax, 32);
    ay += __shfl_xor(ay, 32);
    float2 bp = ((const float2*)b)[c];
    ax = ax * dv + bp.x;
    ay = ay * dv + bp.y;
    float2 ap = ((const float2*)aw)[c];
    float p = ax * ap.x + ay * ap.y;
    for (int off = 16; off; off >>= 1) p += __shfl_xor(p, off);
    float g = 1.0f / (1.0f + expf(-(p + ab[0])));
    if (half == 0) ((float2*)out)[(size_t)v * 32 + c] = make_float2(ax * g, ay * g);
}

// ---------------- launch ----------------

static inline size_t align_up(size_t x, size_t a) { return (x + a - 1) & ~(a - 1); }

extern "C" void kernel_launch(void* const* d_in, const int* in_sizes, int n_in,
                              void* d_out, int out_size, void* d_ws, size_t ws_size,
                              hipStream_t stream) {
    const float* x   = (const float*)d_in[0];
    const void*  ei  = d_in[1];
    const float* W1  = (const float*)d_in[2];
    const float* b1  = (const float*)d_in[3];
    const float* W2  = (const float*)d_in[4];
    const float* b2  = (const float*)d_in[5];
    const float* aw1 = (const float*)d_in[6];
    const float* ab1 = (const float*)d_in[7];
    const float* aw2 = (const float*)d_in[8];
    const float* ab2 = (const float*)d_in[9];
    float* out = (float*)d_out;

    char* w = (char*)d_ws;
    size_t off = 0;
    int*   flag     = (int*)(w + off); off = align_up(off + 4, 256);
    int*   cnt      = (int*)(w + off); off = align_up(off + N_NODES * 4, 256);
    int*   rowstart = (int*)(w + off); off = align_up(off + N_NODES * 4, 256);
    int*   cursor   = (int*)(w + off); off = align_up(off + N_NODES * 4, 256);
    int*   partials = (int*)(w + off); off = align_up(off + 1024 * 4, 256);
    float* dinv     = (float*)(w + off); off = align_up(off + N_NODES * 4, 256);
    int*   colidx   = (int*)(w + off); off = align_up(off + (size_t)N_EDGES * 4, 256);
    u32*   h1s      = (u32*)(w + off); off = align_up(off + (size_t)N_NODES * 64 * 4, 256);
    float* h1g      = (float*)(w + off); off = align_up(off + (size_t)N_NODES * D_HID * 4, 256);
    u32*   h2s      = (u32*)(w + off); off = align_up(off + (size_t)N_NODES * 32 * 4, 256);
    u16*   wt1h     = (u16*)(w + off); off = align_up(off + (size_t)D_IN * D_HID * 2, 256);
    u16*   wt1l     = (u16*)(w + off); off = align_up(off + (size_t)D_IN * D_HID * 2, 256);
    u16*   wt2h     = (u16*)(w + off); off = align_up(off + (size_t)D_HID * D_OUT * 2, 256);
    u16*   wt2l     = (u16*)(w + off); off = align_up(off + (size_t)D_HID * D_OUT * 2, 256);
    (void)ws_size; (void)out_size; (void)n_in; (void)in_sizes;

    hipMemsetAsync(flag, 0, 4, stream);
    hipMemsetAsync(cnt, 0, N_NODES * 4, stream);
    hipMemsetAsync(cursor, 0, N_NODES * 4, stream);

    const int eb = (N_EDGES + 255) / 256;
    const int nb = (N_NODES + 255) / 256;
    const int sb = (N_NODES + SCAN_B - 1) / SCAN_B;

    k_detect<<<1, 256, 0, stream>>>(ei, flag);
    k_wsplit<<<(D_IN * D_HID + 255) / 256, 256, 0, stream>>>(W1, wt1h, wt1l, D_IN, D_HID);
    k_wsplit<<<(D_HID * D_OUT + 255) / 256, 256, 0, stream>>>(W2, wt2h, wt2l, D_HID, D_OUT);
    k_count<<<eb, 256, 0, stream>>>(ei, flag, cnt);
    k_dinv<<<nb, 256, 0, stream>>>(cnt, dinv);
    k_scan1<<<sb, SCAN_B, 0, stream>>>(cnt, rowstart, partials, N_NODES);
    k_scan2<<<1, SCAN_B, 0, stream>>>(partials, sb);
    k_scan3<<<sb, SCAN_B, 0, stream>>>(rowstart, partials, N_NODES);
    k_fill<<<eb, 256, 0, stream>>>(ei, flag, rowstart, cursor, colidx);

    // layer 1: h1s = pack_bf16((x @ W1) * dinv), split-bf16 MFMA
    k_gemm_mfma<D_IN, D_HID><<<(N_NODES + 127) / 128, 256, 0, stream>>>(x, wt1h, wt1l, dinv, h1s, N_NODES);
    k_agg1<<<N_NODES, 64, 0, stream>>>(h1s, rowstart, cnt, colidx, dinv, b1, aw1, ab1, h1g);

    // layer 2: h2s = pack_bf16((h1g @ W2) * dinv), split-bf16 MFMA
    k_gemm_mfma<D_HID, D_OUT><<<(N_NODES + 127) / 128, 256, 0, stream>>>(h1g, wt2h, wt2l, dinv, h2s, N_NODES);
    k_agg2<<<N_NODES, 64, 0, stream>>>(h2s, rowstart, cnt, colidx, dinv, b2, aw2, ab2, out);
}

// Round 2
// 246.583 us; speedup vs baseline: 1.3362x; 1.2152x over previous
//
#include <hip/hip_runtime.h>
#include <math.h>

#define N_NODES 50000
#define N_EDGES 800000
#define D_IN    256
#define D_HID   128
#define D_OUT   64

// bucketed CSR build: bucket = dst >> 8 (256 nodes/bucket)
#define NB 196
#define CH 4096   // edges per scatter1 block (16 per thread)

typedef unsigned int u32;
typedef unsigned short u16;
typedef __attribute__((ext_vector_type(8))) short bf16x8;   // 8 bf16 = 4 VGPRs
typedef __attribute__((ext_vector_type(4))) float f32x4;

__device__ __forceinline__ float bflo(u32 u) {
    union { u32 i; float f; } c; c.i = u << 16; return c.f;
}
__device__ __forceinline__ float bfhi(u32 u) {
    union { u32 i; float f; } c; c.i = u & 0xffff0000u; return c.f;
}
__device__ __forceinline__ u32 pack_bf2(float a, float b) {
    union { float f; u32 i; } ca, cb; ca.f = a; cb.f = b;
    u32 ra = (ca.i + 0x7fffu + ((ca.i >> 16) & 1u)) >> 16;
    u32 rb = (cb.i + 0x7fffu + ((cb.i >> 16) & 1u)) & 0xffff0000u;
    return ra | rb;
}
__device__ __forceinline__ u32 bf16_rne(float f) {
    union { float f; u32 i; } c; c.f = f;
    return (c.i + 0x7fffu + ((c.i >> 16) & 1u)) >> 16;
}
__device__ __forceinline__ float bfbits_to_f32(u32 hb) {
    union { u32 i; float f; } c; c.i = hb << 16; return c.f;
}

// ---------------- edge dtype detection ----------------
__global__ void k_detect(const void* __restrict__ ei, int* __restrict__ flag) {
    int t = threadIdx.x;
    int v = ((const int*)ei)[2 * t + 1];
    if (v != 0) atomicOr(flag, 1);
}

__device__ __forceinline__ int edge_at(const void* ei, int is64, int which, int i) {
    if (is64) return (int)((const long long*)ei)[(size_t)which * N_EDGES + i];
    return ((const int*)ei)[which * N_EDGES + i];
}

// ---------------- bucketed CSR build ----------------

// global bucket histogram (LDS-aggregated)
__global__ __launch_bounds__(256) void k_hist(const void* __restrict__ ei,
                                              const int* __restrict__ flag,
                                              int* __restrict__ bcnt) {
    __shared__ int h[NB];
    int t = threadIdx.x;
    for (int i = t; i < NB; i += 256) h[i] = 0;
    __syncthreads();
    int is64 = (flag[0] == 0);
    for (int i = blockIdx.x * 256 + t; i < N_EDGES; i += gridDim.x * 256) {
        int d = edge_at(ei, is64, 1, i);
        atomicAdd(&h[d >> 8], 1);
    }
    __syncthreads();
    for (int i = t; i < NB; i += 256) if (h[i]) atomicAdd(&bcnt[i], h[i]);
}

// exclusive scan of NB bucket sizes -> bstart; init global cursors
__global__ void k_bscan(const int* __restrict__ bcnt, int* __restrict__ bstart,
                        int* __restrict__ bcur) {
    __shared__ int sm[256];
    int t = threadIdx.x;
    int v = (t < NB) ? bcnt[t] : 0;
    sm[t] = v; __syncthreads();
    for (int off = 1; off < 256; off <<= 1) {
        int a = (t >= off) ? sm[t - off] : 0;
        __syncthreads();
        sm[t] += a;
        __syncthreads();
    }
    if (t < NB) { bstart[t] = sm[t] - v; bcur[t] = sm[t] - v; }
}

// partition edges into bucket-contiguous ebuf as packed (dst<<16)|src
__global__ __launch_bounds__(256) void k_scatter1(const void* __restrict__ ei,
                                                  const int* __restrict__ flag,
                                                  int* __restrict__ bcur,
                                                  u32* __restrict__ ebuf) {
    __shared__ int h[NB], gbase[NB], lc[NB];
    int t = threadIdx.x;
    for (int i = t; i < NB; i += 256) { h[i] = 0; lc[i] = 0; }
    __syncthreads();
    int is64 = (flag[0] == 0);
    int base = blockIdx.x * CH;

    u32 p[CH / 256];
    #pragma unroll
    for (int j = 0; j < CH / 256; ++j) {
        int i = base + j * 256 + t;
        if (i < N_EDGES) {
            int s = edge_at(ei, is64, 0, i);
            int d = edge_at(ei, is64, 1, i);
            p[j] = (u32)s | ((u32)d << 16);
            atomicAdd(&h[d >> 8], 1);
        }
    }
    __syncthreads();
    for (int i = t; i < NB; i += 256) if (h[i]) gbase[i] = atomicAdd(&bcur[i], h[i]);
    __syncthreads();
    #pragma unroll
    for (int j = 0; j < CH / 256; ++j) {
        int i = base + j * 256 + t;
        if (i < N_EDGES) {
            int b = (int)(p[j] >> 24);               // dst >> 8
            int lp = atomicAdd(&lc[b], 1);
            ebuf[gbase[b] + lp] = p[j];              // block-private contiguous run: L2-local
        }
    }
}

// per-bucket: LDS per-node counts/cursors; emit cnt, rowstart, dinv, colidx.
// colidx scatter is confined to the bucket's contiguous range -> stays in L2.
__global__ __launch_bounds__(256) void k_scatter2(const u32* __restrict__ ebuf,
                                                  const int* __restrict__ bstart,
                                                  const int* __restrict__ bcnt,
                                                  int* __restrict__ rowstart,
                                                  int* __restrict__ cnt,
                                                  float* __restrict__ dinv,
                                                  int* __restrict__ colidx) {
    __shared__ int h2[256], lofs[256], cur[256], sm[256];
    int b = blockIdx.x, t = threadIdx.x;
    int e0 = bstart[b], ne = bcnt[b];
    h2[t] = 0; cur[t] = 0;
    __syncthreads();
    for (int i = t; i < ne; i += 256) {
        u32 p = ebuf[e0 + i];
        atomicAdd(&h2[(p >> 16) & 255], 1);
    }
    __syncthreads();
    int v = h2[t]; sm[t] = v; __syncthreads();
    for (int off = 1; off < 256; off <<= 1) {
        int a = (t >= off) ? sm[t - off] : 0;
        __syncthreads();
        sm[t] += a;
        __syncthreads();
    }
    lofs[t] = sm[t] - v;
    __syncthreads();
    int node = (b << 8) + t;
    if (node < N_NODES) {
        rowstart[node] = e0 + lofs[t];
        cnt[node] = v;
        dinv[node] = rsqrtf(1.0f + (float)v);
    }
    for (int i = t; i < ne; i += 256) {
        u32 p = ebuf[e0 + i];
        int dl = (p >> 16) & 255;
        int lp = atomicAdd(&cur[dl], 1);
        colidx[e0 + lofs[dl] + lp] = (int)(p & 0xffffu);
    }
}

// ---------------- W pre-split: W[k][c] f32 -> Wt_hi/Wt_lo[c][k] bf16 ----------------
__global__ void k_wsplit(const float* __restrict__ W, u16* __restrict__ tHi,
                         u16* __restrict__ tLo, int K, int NF) {
    int i = blockIdx.x * 256 + threadIdx.x;
    if (i >= K * NF) return;
    int k = i / NF, c = i - k * NF;
    float f = W[i];
    u32 hb = bf16_rne(f);
    u32 lb = bf16_rne(f - bfbits_to_f32(hb));
    tHi[(size_t)c * K + k] = (u16)hb;
    tLo[(size_t)c * K + k] = (u16)lb;
}

// ---- MFMA GEMM: Cp[r,:] = pack_bf16( (A[r,:] @ W) * dinv[r] ), split-bf16 3-term ----
template <int K, int NF>
__global__ __launch_bounds__(256) void k_gemm_mfma(
    const float* __restrict__ A, const u16* __restrict__ tHi,
    const u16* __restrict__ tLo, const float* __restrict__ dinv,
    u32* __restrict__ Cp, int M) {
    constexpr int NT = NF / 16;
    constexpr int LDK = 40;
    __shared__ u16 aH[128][LDK], aL[128][LDK];
    __shared__ u16 wH[NF][LDK], wL[NF][LDK];

    const int t = threadIdx.x;
    const int lane = t & 63, wv = t >> 6;
    const int m0 = blockIdx.x * 128;
    const int lr = lane & 15, lk = (lane >> 4) * 8;

    f32x4 acc[2][NT] = {};

    const int arow = t >> 1;
    const int akq = (t & 1) * 16;
    const bool aok = (m0 + arow) < M;
    const float* asrc = A + (size_t)(m0 + arow) * K + akq;

    for (int ks = 0; ks < K; ks += 32) {
        {
            float buf[16];
            #pragma unroll
            for (int j = 0; j < 16; ++j) buf[j] = 0.0f;
            if (aok) {
                const float4* p = (const float4*)(asrc + ks);
                float4 v0 = p[0], v1 = p[1], v2 = p[2], v3 = p[3];
                buf[0] = v0.x; buf[1] = v0.y; buf[2]  = v0.z; buf[3]  = v0.w;
                buf[4] = v1.x; buf[5] = v1.y; buf[6]  = v1.z; buf[7]  = v1.w;
                buf[8] = v2.x; buf[9] = v2.y; buf[10] = v2.z; buf[11] = v2.w;
                buf[12] = v3.x; buf[13] = v3.y; buf[14] = v3.z; buf[15] = v3.w;
            }
            u32 h[16], l[16];
            #pragma unroll
            for (int j = 0; j < 16; ++j) {
                h[j] = bf16_rne(buf[j]);
                l[j] = bf16_rne(buf[j] - bfbits_to_f32(h[j]));
            }
            uint4 hv0 = make_uint4(h[0] | (h[1] << 16), h[2] | (h[3] << 16),
                                   h[4] | (h[5] << 16), h[6] | (h[7] << 16));
            uint4 hv1 = make_uint4(h[8] | (h[9] << 16), h[10] | (h[11] << 16),
                                   h[12] | (h[13] << 16), h[14] | (h[15] << 16));
            uint4 lv0 = make_uint4(l[0] | (l[1] << 16), l[2] | (l[3] << 16),
                                   l[4] | (l[5] << 16), l[6] | (l[7] << 16));
            uint4 lv1 = make_uint4(l[8] | (l[9] << 16), l[10] | (l[11] << 16),
                                   l[12] | (l[13] << 16), l[14] | (l[15] << 16));
            *(uint4*)&aH[arow][akq + 0] = hv0;
            *(uint4*)&aH[arow][akq + 8] = hv1;
            *(uint4*)&aL[arow][akq + 0] = lv0;
            *(uint4*)&aL[arow][akq + 8] = lv1;
        }
        #pragma unroll
        for (int idx = t; idx < NF * 4; idx += 256) {
            int col = idx >> 2;
            int k8 = (idx & 3) * 8;
            *(uint4*)&wH[col][k8] = *(const uint4*)&tHi[(size_t)col * K + ks + k8];
            *(uint4*)&wL[col][k8] = *(const uint4*)&tLo[(size_t)col * K + ks + k8];
        }
        __syncthreads();

        bf16x8 afH[2], afL[2];
        #pragma unroll
        for (int mt = 0; mt < 2; ++mt) {
            int r = wv * 32 + mt * 16 + lr;
            afH[mt] = *(const bf16x8*)&aH[r][lk];
            afL[mt] = *(const bf16x8*)&aL[r][lk];
        }
        #pragma unroll
        for (int nt = 0; nt < NT; ++nt) {
            bf16x8 bh = *(const bf16x8*)&wH[nt * 16 + lr][lk];
            bf16x8 bl = *(const bf16x8*)&wL[nt * 16 + lr][lk];
            #pragma unroll
            for (int mt = 0; mt < 2; ++mt) {
                acc[mt][nt] = __builtin_amdgcn_mfma_f32_16x16x32_bf16(afH[mt], bh, acc[mt][nt], 0, 0, 0);
                acc[mt][nt] = __builtin_amdgcn_mfma_f32_16x16x32_bf16(afL[mt], bh, acc[mt][nt], 0, 0, 0);
                acc[mt][nt] = __builtin_amdgcn_mfma_f32_16x16x32_bf16(afH[mt], bl, acc[mt][nt], 0, 0, 0);
            }
        }
        __syncthreads();
    }

    #pragma unroll
    for (int mt = 0; mt < 2; ++mt) {
        #pragma unroll
        for (int r = 0; r < 4; ++r) {
            int row = m0 + wv * 32 + mt * 16 + (lane >> 4) * 4 + r;
            float dv = (row < M) ? dinv[row] : 0.0f;
            #pragma unroll
            for (int nt = 0; nt < NT; ++nt) {
                float v = acc[mt][nt][r] * dv;
                float vn = __shfl_xor(v, 1);
                if (!(lane & 1) && row < M) {
                    Cp[(size_t)row * (NF / 2) + nt * 8 + (lr >> 1)] = pack_bf2(v, vn);
                }
            }
        }
    }
}

// ---------------- fused aggregate + bias (+relu) + sigmoid gate ----------------

__global__ void k_agg1(const u32* __restrict__ hs, const int* __restrict__ rowstart,
                       const int* __restrict__ cnt, const int* __restrict__ colidx,
                       const float* __restrict__ dinv,
                       const float* __restrict__ b, const float* __restrict__ aw,
                       const float* __restrict__ ab, float* __restrict__ out) {
    int v = blockIdx.x;
    int l = threadIdx.x;
    float dv = dinv[v];
    u32 su = hs[(size_t)v * 64 + l];
    float ax = bflo(su), ay = bfhi(su);
    int start = rowstart[v], len = cnt[v];
    const int* cx = colidx + start;
    int j = 0;
    for (; j + 4 <= len; j += 4) {
        int s0 = cx[j], s1 = cx[j + 1], s2 = cx[j + 2], s3 = cx[j + 3];
        u32 u0 = hs[(size_t)s0 * 64 + l];
        u32 u1 = hs[(size_t)s1 * 64 + l];
        u32 u2 = hs[(size_t)s2 * 64 + l];
        u32 u3 = hs[(size_t)s3 * 64 + l];
        ax += bflo(u0) + bflo(u1) + bflo(u2) + bflo(u3);
        ay += bfhi(u0) + bfhi(u1) + bfhi(u2) + bfhi(u3);
    }
    for (; j < len; ++j) {
        u32 u = hs[(size_t)cx[j] * 64 + l];
        ax += bflo(u); ay += bfhi(u);
    }
    float2 bp = ((const float2*)b)[l];
    ax = fmaxf(ax * dv + bp.x, 0.0f);
    ay = fmaxf(ay * dv + bp.y, 0.0f);
    float2 ap = ((const float2*)aw)[l];
    float p = ax * ap.x + ay * ap.y;
    for (int off = 32; off; off >>= 1) p += __shfl_xor(p, off);
    float g = 1.0f / (1.0f + expf(-(p + ab[0])));
    ((float2*)out)[(size_t)v * 64 + l] = make_float2(ax * g, ay * g);
}

__global__ void k_agg2(const u32* __restrict__ hs, const int* __restrict__ rowstart,
                       const int* __restrict__ cnt, const int* __restrict__ colidx,
                       const float* __restrict__ dinv,
                       const float* __restrict__ b, const float* __restrict__ aw,
                       const float* __restrict__ ab, float* __restrict__ out) {
    int v = blockIdx.x;
    int l = threadIdx.x;
    int c = l & 31, half = l >> 5;
    float dv = dinv[v];
    float ax = 0.0f, ay = 0.0f;
    if (half == 0) {
        u32 su = hs[(size_t)v * 32 + c];
        ax = bflo(su); ay = bfhi(su);
    }
    int start = rowstart[v], len = cnt[v];
    const int* cx = colidx + start;
    int j = half;
    for (; j + 2 < len; j += 4) {
        int s0 = cx[j], s1 = cx[j + 2];
        u32 u0 = hs[(size_t)s0 * 32 + c];
        u32 u1 = hs[(size_t)s1 * 32 + c];
        ax += bflo(u0) + bflo(u1);
        ay += bfhi(u0) + bfhi(u1);
    }
    if (j < len) {
        u32 u = hs[(size_t)cx[j] * 32 + c];
        ax += bflo(u); ay += bfhi(u);
    }
    ax += __shfl_xor(ax, 32);
    ay += __shfl_xor(ay, 32);
    float2 bp = ((const float2*)b)[c];
    ax = ax * dv + bp.x;
    ay = ay * dv + bp.y;
    float2 ap = ((const float2*)aw)[c];
    float p = ax * ap.x + ay * ap.y;
    for (int off = 16; off; off >>= 1) p += __shfl_xor(p, off);
    float g = 1.0f / (1.0f + expf(-(p + ab[0])));
    if (half == 0) ((float2*)out)[(size_t)v * 32 + c] = make_float2(ax * g, ay * g);
}

// ---------------- launch ----------------

static inline size_t align_up(size_t x, size_t a) { return (x + a - 1) & ~(a - 1); }

extern "C" void kernel_launch(void* const* d_in, const int* in_sizes, int n_in,
                              void* d_out, int out_size, void* d_ws, size_t ws_size,
                              hipStream_t stream) {
    const float* x   = (const float*)d_in[0];
    const void*  ei  = d_in[1];
    const float* W1  = (const float*)d_in[2];
    const float* b1  = (const float*)d_in[3];
    const float* W2  = (const float*)d_in[4];
    const float* b2  = (const float*)d_in[5];
    const float* aw1 = (const float*)d_in[6];
    const float* ab1 = (const float*)d_in[7];
    const float* aw2 = (const float*)d_in[8];
    const float* ab2 = (const float*)d_in[9];
    float* out = (float*)d_out;

    char* w = (char*)d_ws;
    size_t off = 0;
    int*   flag     = (int*)(w + off); off = align_up(off + 4, 256);
    int*   bcnt     = (int*)(w + off); off = align_up(off + NB * 4, 256);
    int*   bstart   = (int*)(w + off); off = align_up(off + NB * 4, 256);
    int*   bcur     = (int*)(w + off); off = align_up(off + NB * 4, 256);
    int*   cnt      = (int*)(w + off); off = align_up(off + N_NODES * 4, 256);
    int*   rowstart = (int*)(w + off); off = align_up(off + N_NODES * 4, 256);
    float* dinv     = (float*)(w + off); off = align_up(off + N_NODES * 4, 256);
    u32*   ebuf     = (u32*)(w + off); off = align_up(off + (size_t)N_EDGES * 4, 256);
    int*   colidx   = (int*)(w + off); off = align_up(off + (size_t)N_EDGES * 4, 256);
    u32*   h1s      = (u32*)(w + off); off = align_up(off + (size_t)N_NODES * 64 * 4, 256);
    float* h1g      = (float*)(w + off); off = align_up(off + (size_t)N_NODES * D_HID * 4, 256);
    u32*   h2s      = (u32*)(w + off); off = align_up(off + (size_t)N_NODES * 32 * 4, 256);
    u16*   wt1h     = (u16*)(w + off); off = align_up(off + (size_t)D_IN * D_HID * 2, 256);
    u16*   wt1l     = (u16*)(w + off); off = align_up(off + (size_t)D_IN * D_HID * 2, 256);
    u16*   wt2h     = (u16*)(w + off); off = align_up(off + (size_t)D_HID * D_OUT * 2, 256);
    u16*   wt2l     = (u16*)(w + off); off = align_up(off + (size_t)D_HID * D_OUT * 2, 256);
    (void)ws_size; (void)out_size; (void)n_in; (void)in_sizes;

    hipMemsetAsync(flag, 0, 4, stream);
    hipMemsetAsync(bcnt, 0, NB * 4, stream);

    k_detect<<<1, 256, 0, stream>>>(ei, flag);
    k_wsplit<<<(D_IN * D_HID + 255) / 256, 256, 0, stream>>>(W1, wt1h, wt1l, D_IN, D_HID);
    k_wsplit<<<(D_HID * D_OUT + 255) / 256, 256, 0, stream>>>(W2, wt2h, wt2l, D_HID, D_OUT);

    k_hist<<<256, 256, 0, stream>>>(ei, flag, bcnt);
    k_bscan<<<1, 256, 0, stream>>>(bcnt, bstart, bcur);
    k_scatter1<<<(N_EDGES + CH - 1) / CH, 256, 0, stream>>>(ei, flag, bcur, ebuf);
    k_scatter2<<<NB, 256, 0, stream>>>(ebuf, bstart, bcnt, rowstart, cnt, dinv, colidx);

    // layer 1: h1s = pack_bf16((x @ W1) * dinv), split-bf16 MFMA
    k_gemm_mfma<D_IN, D_HID><<<(N_NODES + 127) / 128, 256, 0, stream>>>(x, wt1h, wt1l, dinv, h1s, N_NODES);
    k_agg1<<<N_NODES, 64, 0, stream>>>(h1s, rowstart, cnt, colidx, dinv, b1, aw1, ab1, h1g);

    // layer 2: h2s = pack_bf16((h1g @ W2) * dinv), split-bf16 MFMA
    k_gemm_mfma<D_HID, D_OUT><<<(N_NODES + 127) / 128, 256, 0, stream>>>(h1g, wt2h, wt2l, dinv, h2s, N_NODES);
    k_agg2<<<N_NODES, 64, 0, stream>>>(h2s, rowstart, cnt, colidx, dinv, b2, aw2, ab2, out);
}

// Round 3
// 237.977 us; speedup vs baseline: 1.3846x; 1.0362x over previous
//
#include <hip/hip_runtime.h>
#include <math.h>

#define N_NODES 50000
#define N_EDGES 800000
#define D_IN    256
#define D_HID   128
#define D_OUT   64

// bucketed CSR build: bucket = dst >> 8 (256 nodes/bucket)
#define NB 196
#define CH 4096   // edges per scatter1 block (16 per thread)

typedef unsigned int u32;
typedef unsigned short u16;
typedef __attribute__((ext_vector_type(8))) short bf16x8;   // 8 bf16 = 4 VGPRs
typedef __attribute__((ext_vector_type(4))) float f32x4;

__device__ __forceinline__ float bflo(u32 u) {
    union { u32 i; float f; } c; c.i = u << 16; return c.f;
}
__device__ __forceinline__ float bfhi(u32 u) {
    union { u32 i; float f; } c; c.i = u & 0xffff0000u; return c.f;
}
__device__ __forceinline__ u32 pack_bf2(float a, float b) {
    union { float f; u32 i; } ca, cb; ca.f = a; cb.f = b;
    u32 ra = (ca.i + 0x7fffu + ((ca.i >> 16) & 1u)) >> 16;
    u32 rb = (cb.i + 0x7fffu + ((cb.i >> 16) & 1u)) & 0xffff0000u;
    return ra | rb;
}
__device__ __forceinline__ u32 bf16_rne(float f) {
    union { float f; u32 i; } c; c.f = f;
    return (c.i + 0x7fffu + ((c.i >> 16) & 1u)) >> 16;
}
__device__ __forceinline__ float bfbits_to_f32(u32 hb) {
    union { u32 i; float f; } c; c.i = hb << 16; return c.f;
}

__device__ __forceinline__ int edge_at(const void* ei, int is64, int which, int i) {
    if (is64) return (int)((const long long*)ei)[(size_t)which * N_EDGES + i];
    return ((const int*)ei)[which * N_EDGES + i];
}

// per-block edge dtype detection: odd 32-bit words of the first 256 entries are
// all zero iff layout is int64 (values < 2^31). Same logic as the old k_detect,
// replicated per block to kill the extra dispatch + flag dependency.
__device__ __forceinline__ int detect_is64(const void* ei, int t, int* s_is32) {
    if (t == 0) *s_is32 = 0;
    __syncthreads();
    if (t < 256) {
        int vv = ((const int*)ei)[2 * t + 1];
        if (vv != 0) atomicOr(s_is32, 1);
    }
    __syncthreads();
    return (*s_is32 == 0);
}

// ---------------- bucketed CSR build ----------------

// global bucket histogram (LDS-aggregated)
__global__ __launch_bounds__(256) void k_hist(const void* __restrict__ ei,
                                              int* __restrict__ bcnt) {
    __shared__ int h[NB];
    __shared__ int s_is32;
    int t = threadIdx.x;
    int is64 = detect_is64(ei, t, &s_is32);
    for (int i = t; i < NB; i += 256) h[i] = 0;
    __syncthreads();
    for (int i = blockIdx.x * 256 + t; i < N_EDGES; i += gridDim.x * 256) {
        int d = edge_at(ei, is64, 1, i);
        atomicAdd(&h[d >> 8], 1);
    }
    __syncthreads();
    for (int i = t; i < NB; i += 256) if (h[i]) atomicAdd(&bcnt[i], h[i]);
}

// exclusive scan of NB bucket sizes -> bstart; init global cursors
__global__ void k_bscan(const int* __restrict__ bcnt, int* __restrict__ bstart,
                        int* __restrict__ bcur) {
    __shared__ int sm[256];
    int t = threadIdx.x;
    int v = (t < NB) ? bcnt[t] : 0;
    sm[t] = v; __syncthreads();
    for (int off = 1; off < 256; off <<= 1) {
        int a = (t >= off) ? sm[t - off] : 0;
        __syncthreads();
        sm[t] += a;
        __syncthreads();
    }
    if (t < NB) { bstart[t] = sm[t] - v; bcur[t] = sm[t] - v; }
}

// partition edges into bucket-contiguous ebuf as packed (dst<<16)|src
__global__ __launch_bounds__(256) void k_scatter1(const void* __restrict__ ei,
                                                  int* __restrict__ bcur,
                                                  u32* __restrict__ ebuf) {
    __shared__ int h[NB], gbase[NB], lc[NB];
    __shared__ int s_is32;
    int t = threadIdx.x;
    int is64 = detect_is64(ei, t, &s_is32);
    for (int i = t; i < NB; i += 256) { h[i] = 0; lc[i] = 0; }
    __syncthreads();
    int base = blockIdx.x * CH;

    u32 p[CH / 256];
    #pragma unroll
    for (int j = 0; j < CH / 256; ++j) {
        int i = base + j * 256 + t;
        if (i < N_EDGES) {
            int s = edge_at(ei, is64, 0, i);
            int d = edge_at(ei, is64, 1, i);
            p[j] = (u32)s | ((u32)d << 16);
            atomicAdd(&h[d >> 8], 1);
        }
    }
    __syncthreads();
    for (int i = t; i < NB; i += 256) if (h[i]) gbase[i] = atomicAdd(&bcur[i], h[i]);
    __syncthreads();
    #pragma unroll
    for (int j = 0; j < CH / 256; ++j) {
        int i = base + j * 256 + t;
        if (i < N_EDGES) {
            int b = (int)(p[j] >> 24);               // dst >> 8
            int lp = atomicAdd(&lc[b], 1);
            ebuf[gbase[b] + lp] = p[j];              // block-private contiguous run: L2-local
        }
    }
}

// per-bucket: LDS per-node counts/cursors; emit cnt, rowstart, dinv, colidx.
__global__ __launch_bounds__(256) void k_scatter2(const u32* __restrict__ ebuf,
                                                  const int* __restrict__ bstart,
                                                  const int* __restrict__ bcnt,
                                                  int* __restrict__ rowstart,
                                                  int* __restrict__ cnt,
                                                  float* __restrict__ dinv,
                                                  int* __restrict__ colidx) {
    __shared__ int h2[256], lofs[256], cur[256], sm[256];
    int b = blockIdx.x, t = threadIdx.x;
    int e0 = bstart[b], ne = bcnt[b];
    h2[t] = 0; cur[t] = 0;
    __syncthreads();
    for (int i = t; i < ne; i += 256) {
        u32 p = ebuf[e0 + i];
        atomicAdd(&h2[(p >> 16) & 255], 1);
    }
    __syncthreads();
    int v = h2[t]; sm[t] = v; __syncthreads();
    for (int off = 1; off < 256; off <<= 1) {
        int a = (t >= off) ? sm[t - off] : 0;
        __syncthreads();
        sm[t] += a;
        __syncthreads();
    }
    lofs[t] = sm[t] - v;
    __syncthreads();
    int node = (b << 8) + t;
    if (node < N_NODES) {
        rowstart[node] = e0 + lofs[t];
        cnt[node] = v;
        dinv[node] = rsqrtf(1.0f + (float)v);
    }
    for (int i = t; i < ne; i += 256) {
        u32 p = ebuf[e0 + i];
        int dl = (p >> 16) & 255;
        int lp = atomicAdd(&cur[dl], 1);
        colidx[e0 + lofs[dl] + lp] = (int)(p & 0xffffu);
    }
}

// ------ W pre-split (both layers in one launch): W[k][c] f32 -> hi/lo bf16 [c][k] ------
__global__ void k_wsplit(const float* __restrict__ W1, u16* __restrict__ t1h,
                         u16* __restrict__ t1l, const float* __restrict__ W2,
                         u16* __restrict__ t2h, u16* __restrict__ t2l) {
    int i = blockIdx.x * 256 + threadIdx.x;
    if (i < D_IN * D_HID) {
        int k = i / D_HID, c = i - k * D_HID;
        float f = W1[i];
        u32 hb = bf16_rne(f);
        u32 lb = bf16_rne(f - bfbits_to_f32(hb));
        t1h[(size_t)c * D_IN + k] = (u16)hb;
        t1l[(size_t)c * D_IN + k] = (u16)lb;
    }
    int j = i - D_IN * D_HID;
    if (j >= 0 && j < D_HID * D_OUT) {
        int k = j / D_OUT, c = j - k * D_OUT;
        float f = W2[j];
        u32 hb = bf16_rne(f);
        u32 lb = bf16_rne(f - bfbits_to_f32(hb));
        t2h[(size_t)c * D_HID + k] = (u16)hb;
        t2l[(size_t)c * D_HID + k] = (u16)lb;
    }
}

// ---- MFMA GEMM: Cp[r,:] = pack_bf16( (A[r,:] @ W) * dinv[r] ), split-bf16 3-term ----
template <int K, int NF>
__global__ __launch_bounds__(256) void k_gemm_mfma(
    const float* __restrict__ A, const u16* __restrict__ tHi,
    const u16* __restrict__ tLo, const float* __restrict__ dinv,
    u32* __restrict__ Cp, int M) {
    constexpr int NT = NF / 16;
    constexpr int LDK = 40;
    __shared__ u16 aH[128][LDK], aL[128][LDK];
    __shared__ u16 wH[NF][LDK], wL[NF][LDK];

    const int t = threadIdx.x;
    const int lane = t & 63, wv = t >> 6;
    const int m0 = blockIdx.x * 128;
    const int lr = lane & 15, lk = (lane >> 4) * 8;

    f32x4 acc[2][NT] = {};

    const int arow = t >> 1;
    const int akq = (t & 1) * 16;
    const bool aok = (m0 + arow) < M;
    const float* asrc = A + (size_t)(m0 + arow) * K + akq;

    for (int ks = 0; ks < K; ks += 32) {
        {
            float buf[16];
            #pragma unroll
            for (int j = 0; j < 16; ++j) buf[j] = 0.0f;
            if (aok) {
                const float4* p = (const float4*)(asrc + ks);
                float4 v0 = p[0], v1 = p[1], v2 = p[2], v3 = p[3];
                buf[0] = v0.x; buf[1] = v0.y; buf[2]  = v0.z; buf[3]  = v0.w;
                buf[4] = v1.x; buf[5] = v1.y; buf[6]  = v1.z; buf[7]  = v1.w;
                buf[8] = v2.x; buf[9] = v2.y; buf[10] = v2.z; buf[11] = v2.w;
                buf[12] = v3.x; buf[13] = v3.y; buf[14] = v3.z; buf[15] = v3.w;
            }
            u32 h[16], l[16];
            #pragma unroll
            for (int j = 0; j < 16; ++j) {
                h[j] = bf16_rne(buf[j]);
                l[j] = bf16_rne(buf[j] - bfbits_to_f32(h[j]));
            }
            uint4 hv0 = make_uint4(h[0] | (h[1] << 16), h[2] | (h[3] << 16),
                                   h[4] | (h[5] << 16), h[6] | (h[7] << 16));
            uint4 hv1 = make_uint4(h[8] | (h[9] << 16), h[10] | (h[11] << 16),
                                   h[12] | (h[13] << 16), h[14] | (h[15] << 16));
            uint4 lv0 = make_uint4(l[0] | (l[1] << 16), l[2] | (l[3] << 16),
                                   l[4] | (l[5] << 16), l[6] | (l[7] << 16));
            uint4 lv1 = make_uint4(l[8] | (l[9] << 16), l[10] | (l[11] << 16),
                                   l[12] | (l[13] << 16), l[14] | (l[15] << 16));
            *(uint4*)&aH[arow][akq + 0] = hv0;
            *(uint4*)&aH[arow][akq + 8] = hv1;
            *(uint4*)&aL[arow][akq + 0] = lv0;
            *(uint4*)&aL[arow][akq + 8] = lv1;
        }
        #pragma unroll
        for (int idx = t; idx < NF * 4; idx += 256) {
            int col = idx >> 2;
            int k8 = (idx & 3) * 8;
            *(uint4*)&wH[col][k8] = *(const uint4*)&tHi[(size_t)col * K + ks + k8];
            *(uint4*)&wL[col][k8] = *(const uint4*)&tLo[(size_t)col * K + ks + k8];
        }
        __syncthreads();

        bf16x8 afH[2], afL[2];
        #pragma unroll
        for (int mt = 0; mt < 2; ++mt) {
            int r = wv * 32 + mt * 16 + lr;
            afH[mt] = *(const bf16x8*)&aH[r][lk];
            afL[mt] = *(const bf16x8*)&aL[r][lk];
        }
        #pragma unroll
        for (int nt = 0; nt < NT; ++nt) {
            bf16x8 bh = *(const bf16x8*)&wH[nt * 16 + lr][lk];
            bf16x8 bl = *(const bf16x8*)&wL[nt * 16 + lr][lk];
            #pragma unroll
            for (int mt = 0; mt < 2; ++mt) {
                acc[mt][nt] = __builtin_amdgcn_mfma_f32_16x16x32_bf16(afH[mt], bh, acc[mt][nt], 0, 0, 0);
                acc[mt][nt] = __builtin_amdgcn_mfma_f32_16x16x32_bf16(afL[mt], bh, acc[mt][nt], 0, 0, 0);
                acc[mt][nt] = __builtin_amdgcn_mfma_f32_16x16x32_bf16(afH[mt], bl, acc[mt][nt], 0, 0, 0);
            }
        }
        __syncthreads();
    }

    #pragma unroll
    for (int mt = 0; mt < 2; ++mt) {
        #pragma unroll
        for (int r = 0; r < 4; ++r) {
            int row = m0 + wv * 32 + mt * 16 + (lane >> 4) * 4 + r;
            float dv = (row < M) ? dinv[row] : 0.0f;
            #pragma unroll
            for (int nt = 0; nt < NT; ++nt) {
                float v = acc[mt][nt][r] * dv;
                float vn = __shfl_xor(v, 1);
                if (!(lane & 1) && row < M) {
                    Cp[(size_t)row * (NF / 2) + nt * 8 + (lr >> 1)] = pack_bf2(v, vn);
                }
            }
        }
    }
}

// ---------------- fused aggregate + bias (+relu) + sigmoid gate ----------------
// 256-thread blocks, 4 nodes/block (one per wave) for full occupancy;
// 8 neighbor rows in flight per wave for latency hiding.

__global__ __launch_bounds__(256) void k_agg1(
        const u32* __restrict__ hs, const int* __restrict__ rowstart,
        const int* __restrict__ cnt, const int* __restrict__ colidx,
        const float* __restrict__ dinv,
        const float* __restrict__ b, const float* __restrict__ aw,
        const float* __restrict__ ab, float* __restrict__ out) {
    int v = blockIdx.x * 4 + (threadIdx.x >> 6);
    int l = threadIdx.x & 63;
    if (v >= N_NODES) return;
    float dv = dinv[v];
    u32 su = hs[(size_t)v * 64 + l];
    float ax = bflo(su), ay = bfhi(su);
    int start = rowstart[v], len = cnt[v];
    const int* cx = colidx + start;
    int j = 0;
    for (; j + 8 <= len; j += 8) {
        int s0 = cx[j], s1 = cx[j + 1], s2 = cx[j + 2], s3 = cx[j + 3];
        int s4 = cx[j + 4], s5 = cx[j + 5], s6 = cx[j + 6], s7 = cx[j + 7];
        u32 u0 = hs[(size_t)s0 * 64 + l];
        u32 u1 = hs[(size_t)s1 * 64 + l];
        u32 u2 = hs[(size_t)s2 * 64 + l];
        u32 u3 = hs[(size_t)s3 * 64 + l];
        u32 u4 = hs[(size_t)s4 * 64 + l];
        u32 u5 = hs[(size_t)s5 * 64 + l];
        u32 u6 = hs[(size_t)s6 * 64 + l];
        u32 u7 = hs[(size_t)s7 * 64 + l];
        ax += bflo(u0) + bflo(u1) + bflo(u2) + bflo(u3)
            + bflo(u4) + bflo(u5) + bflo(u6) + bflo(u7);
        ay += bfhi(u0) + bfhi(u1) + bfhi(u2) + bfhi(u3)
            + bfhi(u4) + bfhi(u5) + bfhi(u6) + bfhi(u7);
    }
    for (; j + 4 <= len; j += 4) {
        int s0 = cx[j], s1 = cx[j + 1], s2 = cx[j + 2], s3 = cx[j + 3];
        u32 u0 = hs[(size_t)s0 * 64 + l];
        u32 u1 = hs[(size_t)s1 * 64 + l];
        u32 u2 = hs[(size_t)s2 * 64 + l];
        u32 u3 = hs[(size_t)s3 * 64 + l];
        ax += bflo(u0) + bflo(u1) + bflo(u2) + bflo(u3);
        ay += bfhi(u0) + bfhi(u1) + bfhi(u2) + bfhi(u3);
    }
    for (; j < len; ++j) {
        u32 u = hs[(size_t)cx[j] * 64 + l];
        ax += bflo(u); ay += bfhi(u);
    }
    float2 bp = ((const float2*)b)[l];
    ax = fmaxf(ax * dv + bp.x, 0.0f);
    ay = fmaxf(ay * dv + bp.y, 0.0f);
    float2 ap = ((const float2*)aw)[l];
    float p = ax * ap.x + ay * ap.y;
    for (int off = 32; off; off >>= 1) p += __shfl_xor(p, off);
    float g = 1.0f / (1.0f + expf(-(p + ab[0])));
    ((float2*)out)[(size_t)v * 64 + l] = make_float2(ax * g, ay * g);
}

// layer 2: 64 feats = 32 u32/row; wave split into 2 half-waves on alternating
// neighbors, each half 4 rows in flight (8/wave).
__global__ __launch_bounds__(256) void k_agg2(
        const u32* __restrict__ hs, const int* __restrict__ rowstart,
        const int* __restrict__ cnt, const int* __restrict__ colidx,
        const float* __restrict__ dinv,
        const float* __restrict__ b, const float* __restrict__ aw,
        const float* __restrict__ ab, float* __restrict__ out) {
    int v = blockIdx.x * 4 + (threadIdx.x >> 6);
    int l = threadIdx.x & 63;
    if (v >= N_NODES) return;
    int c = l & 31, half = l >> 5;
    float dv = dinv[v];
    float ax = 0.0f, ay = 0.0f;
    if (half == 0) {
        u32 su = hs[(size_t)v * 32 + c];
        ax = bflo(su); ay = bfhi(su);
    }
    int start = rowstart[v], len = cnt[v];
    const int* cx = colidx + start;
    int j = half;
    for (; j + 6 < len; j += 8) {
        int s0 = cx[j], s1 = cx[j + 2], s2 = cx[j + 4], s3 = cx[j + 6];
        u32 u0 = hs[(size_t)s0 * 32 + c];
        u32 u1 = hs[(size_t)s1 * 32 + c];
        u32 u2 = hs[(size_t)s2 * 32 + c];
        u32 u3 = hs[(size_t)s3 * 32 + c];
        ax += bflo(u0) + bflo(u1) + bflo(u2) + bflo(u3);
        ay += bfhi(u0) + bfhi(u1) + bfhi(u2) + bfhi(u3);
    }
    for (; j + 2 < len; j += 4) {
        int s0 = cx[j], s1 = cx[j + 2];
        u32 u0 = hs[(size_t)s0 * 32 + c];
        u32 u1 = hs[(size_t)s1 * 32 + c];
        ax += bflo(u0) + bflo(u1);
        ay += bfhi(u0) + bfhi(u1);
    }
    if (j < len) {
        u32 u = hs[(size_t)cx[j] * 32 + c];
        ax += bflo(u); ay += bfhi(u);
    }
    ax += __shfl_xor(ax, 32);
    ay += __shfl_xor(ay, 32);
    float2 bp = ((const float2*)b)[c];
    ax = ax * dv + bp.x;
    ay = ay * dv + bp.y;
    float2 ap = ((const float2*)aw)[c];
    float p = ax * ap.x + ay * ap.y;
    for (int off = 16; off; off >>= 1) p += __shfl_xor(p, off);
    float g = 1.0f / (1.0f + expf(-(p + ab[0])));
    if (half == 0) ((float2*)out)[(size_t)v * 32 + c] = make_float2(ax * g, ay * g);
}

// ---------------- launch ----------------

static inline size_t align_up(size_t x, size_t a) { return (x + a - 1) & ~(a - 1); }

extern "C" void kernel_launch(void* const* d_in, const int* in_sizes, int n_in,
                              void* d_out, int out_size, void* d_ws, size_t ws_size,
                              hipStream_t stream) {
    const float* x   = (const float*)d_in[0];
    const void*  ei  = d_in[1];
    const float* W1  = (const float*)d_in[2];
    const float* b1  = (const float*)d_in[3];
    const float* W2  = (const float*)d_in[4];
    const float* b2  = (const float*)d_in[5];
    const float* aw1 = (const float*)d_in[6];
    const float* ab1 = (const float*)d_in[7];
    const float* aw2 = (const float*)d_in[8];
    const float* ab2 = (const float*)d_in[9];
    float* out = (float*)d_out;

    char* w = (char*)d_ws;
    size_t off = 0;
    int*   bcnt     = (int*)(w + off); off = align_up(off + NB * 4, 256);
    int*   bstart   = (int*)(w + off); off = align_up(off + NB * 4, 256);
    int*   bcur     = (int*)(w + off); off = align_up(off + NB * 4, 256);
    int*   cnt      = (int*)(w + off); off = align_up(off + N_NODES * 4, 256);
    int*   rowstart = (int*)(w + off); off = align_up(off + N_NODES * 4, 256);
    float* dinv     = (float*)(w + off); off = align_up(off + N_NODES * 4, 256);
    u32*   ebuf     = (u32*)(w + off); off = align_up(off + (size_t)N_EDGES * 4, 256);
    int*   colidx   = (int*)(w + off); off = align_up(off + (size_t)N_EDGES * 4, 256);
    u32*   h1s      = (u32*)(w + off); off = align_up(off + (size_t)N_NODES * 64 * 4, 256);
    float* h1g      = (float*)(w + off); off = align_up(off + (size_t)N_NODES * D_HID * 4, 256);
    u32*   h2s      = (u32*)(w + off); off = align_up(off + (size_t)N_NODES * 32 * 4, 256);
    u16*   wt1h     = (u16*)(w + off); off = align_up(off + (size_t)D_IN * D_HID * 2, 256);
    u16*   wt1l     = (u16*)(w + off); off = align_up(off + (size_t)D_IN * D_HID * 2, 256);
    u16*   wt2h     = (u16*)(w + off); off = align_up(off + (size_t)D_HID * D_OUT * 2, 256);
    u16*   wt2l     = (u16*)(w + off); off = align_up(off + (size_t)D_HID * D_OUT * 2, 256);
    (void)ws_size; (void)out_size; (void)n_in; (void)in_sizes;

    hipMemsetAsync(bcnt, 0, NB * 4, stream);

    k_wsplit<<<(D_IN * D_HID + D_HID * D_OUT + 255) / 256, 256, 0, stream>>>(
        W1, wt1h, wt1l, W2, wt2h, wt2l);

    k_hist<<<256, 256, 0, stream>>>(ei, bcnt);
    k_bscan<<<1, 256, 0, stream>>>(bcnt, bstart, bcur);
    k_scatter1<<<(N_EDGES + CH - 1) / CH, 256, 0, stream>>>(ei, bcur, ebuf);
    k_scatter2<<<NB, 256, 0, stream>>>(ebuf, bstart, bcnt, rowstart, cnt, dinv, colidx);

    // layer 1: h1s = pack_bf16((x @ W1) * dinv), split-bf16 MFMA
    k_gemm_mfma<D_IN, D_HID><<<(N_NODES + 127) / 128, 256, 0, stream>>>(x, wt1h, wt1l, dinv, h1s, N_NODES);
    k_agg1<<<(N_NODES + 3) / 4, 256, 0, stream>>>(h1s, rowstart, cnt, colidx, dinv, b1, aw1, ab1, h1g);

    // layer 2: h2s = pack_bf16((h1g @ W2) * dinv), split-bf16 MFMA
    k_gemm_mfma<D_HID, D_OUT><<<(N_NODES + 127) / 128, 256, 0, stream>>>(h1g, wt2h, wt2l, dinv, h2s, N_NODES);
    k_agg2<<<(N_NODES + 3) / 4, 256, 0, stream>>>(h2s, rowstart, cnt, colidx, dinv, b2, aw2, ab2, out);
}